// Round 2
// baseline (3871.243 us; speedup 1.0000x reference)
//
#include <hip/hip_runtime.h>

typedef __bf16 bf16;
typedef __bf16 bf16x8 __attribute__((ext_vector_type(8)));
typedef __bf16 bf16x4 __attribute__((ext_vector_type(4)));
typedef float  f32x4  __attribute__((ext_vector_type(4)));

#define NLAYER 6
#define DMODEL 1024
#define NHEAD  16
#define DHEAD  64
#define FFDIM  4096
#define BATCH  8
#define SEQLEN 512
#define MTOK   (BATCH * SEQLEN)   // 4096 tokens

#define GAS(p) ((const __attribute__((address_space(1))) void*)(p))
#define LAS(p) ((__attribute__((address_space(3))) void*)(p))

// ---------------------------------------------------------------------------
// Dtype detection: scan first 64K 16-bit words of trg. If the buffer is fp32,
// the low half-words of floats have uniform-random "exponent" bits -> ~128
// words with exp==0xFF (inf/nan as bf16). Genuine bf16 N(0,1) data: 0.
// flag=1 -> inputs are fp32;  flag=0 -> inputs are bf16.
// ---------------------------------------------------------------------------
__global__ __launch_bounds__(256) void kdetect(const unsigned short* __restrict__ w,
                                               int* __restrict__ flag)
{
  __shared__ int cnt;
  if (threadIdx.x == 0) cnt = 0;
  __syncthreads();
  int c = 0;
  for (int i = threadIdx.x; i < 65536; i += 256)
    c += (((w[i] >> 7) & 0xFF) == 0xFF);
  atomicAdd(&cnt, c);
  __syncthreads();
  if (threadIdx.x == 0) *flag = (cnt > 16) ? 1 : 0;
}

// ---------------------------------------------------------------------------
// Input conversion: raw (fp32 or bf16 per flag) -> bf16.
// ---------------------------------------------------------------------------
__global__ __launch_bounds__(256) void kcvt(const void* __restrict__ src,
                                            bf16* __restrict__ dst, long n,
                                            const int* __restrict__ flag)
{
  long i = (long)blockIdx.x * 256 + threadIdx.x;
  if (i >= n) return;
  if (*flag) dst[i] = (bf16)((const float*)src)[i];
  else       dst[i] = ((const bf16*)src)[i];
}

// Output writer: bf16 result -> raw output (fp32 or bf16 per flag).
__global__ __launch_bounds__(256) void kout(const bf16* __restrict__ src,
                                            void* __restrict__ dst, long n,
                                            const int* __restrict__ flag)
{
  long i = (long)blockIdx.x * 256 + threadIdx.x;
  if (i >= n) return;
  if (*flag) ((float*)dst)[i] = (float)src[i];
  else       ((bf16*)dst)[i]  = src[i];
}

// ---------------------------------------------------------------------------
// Batched transpose with fused dtype conversion:
// in[ebase + z0*ibs0 + z1*ibs1 + r*ldin + c]  ->  out[z*obs + c*R + r]
// mode=1: source dtype per flag (raw input tensor); mode=0: source is bf16.
// block (32,8), grid (R/32, C/32, nz).
// ---------------------------------------------------------------------------
__global__ __launch_bounds__(256) void ktranspose(
    const void* __restrict__ in, bf16* __restrict__ out,
    int R, int C, int ldin, long ebase, long ibs0, long ibs1, int nb1, long obs,
    const int* __restrict__ flag, int mode)
{
  __shared__ bf16 tile[32][33];
  bool f32in = mode && *flag;
  int z = blockIdx.z;
  long base = ebase + (long)(z / nb1) * ibs0 + (long)(z % nb1) * ibs1;
  bf16* dst = out + (long)z * obs;
  int r0 = blockIdx.x * 32, c0 = blockIdx.y * 32;
  int tx = threadIdx.x, ty = threadIdx.y;
  const float* fp = (const float*)in;
  const bf16*  bp = (const bf16*)in;
#pragma unroll
  for (int i = 0; i < 32; i += 8) {
    long idx = base + (long)(r0 + ty + i) * ldin + (c0 + tx);
    tile[ty + i][tx] = f32in ? (bf16)fp[idx] : bp[idx];
  }
  __syncthreads();
#pragma unroll
  for (int i = 0; i < 32; i += 8)
    dst[(long)(c0 + ty + i) * R + (r0 + tx)] = tile[tx][ty + i];
}

// ---------------------------------------------------------------------------
// Batched NT GEMM: C[M,N] = scale * (A[M,K] @ B[N,K]^T) + bias[N], opt ReLU.
// A, B row-major bf16 with K contiguous; fp32 MFMA accumulate (m97 structure).
// ---------------------------------------------------------------------------
template<int BM, int BN, int WM, int WN, bool RELU>
__global__ __launch_bounds__(256) void kgemm_nt(
    const bf16* __restrict__ A, const bf16* __restrict__ B, bf16* __restrict__ C,
    const bf16* __restrict__ bias, int K, int lda, int ldb, int ldc,
    long aB0, long aB1, long bB0, long bB1, long cB0, long cB1,
    int nb1, float scale)
{
  constexpr int TM = BM / WM, TN = BN / WN;
  constexpr int FM = TM / 16, FN = TN / 16;
  __shared__ __align__(16) bf16 At[BM * 64];
  __shared__ __align__(16) bf16 Bt[BN * 64];

  int z = blockIdx.z, z0 = z / nb1, z1 = z % nb1;
  const bf16* Ab = A + z0 * aB0 + z1 * aB1;
  const bf16* Bb = B + z0 * bB0 + z1 * bB1;
  bf16* Cb = C + z0 * cB0 + z1 * cB1;

  int row0 = blockIdx.x * BM, col0 = blockIdx.y * BN;
  int t = threadIdx.x;
  int lane = t & 63, w = t >> 6;
  int wm = w / WN, wn = w % WN;
  int m16 = lane & 15, quad = lane >> 4;

  f32x4 acc[FM][FN];
#pragma unroll
  for (int i = 0; i < FM; i++)
#pragma unroll
    for (int j = 0; j < FN; j++)
      acc[i][j] = f32x4{0.f, 0.f, 0.f, 0.f};

  int sr = t >> 3, sc = (t & 7) * 8;     // thread t stages 16B: row t/8, col (t%8)*8
  const bf16* ga = Ab + (long)(row0 + sr) * lda + sc;
  const bf16* gb = Bb + (long)(col0 + sr) * ldb + sc;

  for (int k0 = 0; k0 < K; k0 += 64) {
#pragma unroll
    for (int i = 0; i < BM / 32; i++)
      __builtin_amdgcn_global_load_lds(GAS(ga + (long)i * 32 * lda + k0),
                                       LAS(&At[t * 8 + i * 2048]), 16, 0, 0);
#pragma unroll
    for (int i = 0; i < BN / 32; i++)
      __builtin_amdgcn_global_load_lds(GAS(gb + (long)i * 32 * ldb + k0),
                                       LAS(&Bt[t * 8 + i * 2048]), 16, 0, 0);
    __syncthreads();
#pragma unroll
    for (int s = 0; s < 2; s++) {
      bf16x8 af[FM], bfr[FN];
#pragma unroll
      for (int i = 0; i < FM; i++)
        af[i] = *(const bf16x8*)&At[(wm * TM + i * 16 + m16) * 64 + s * 32 + quad * 8];
#pragma unroll
      for (int j = 0; j < FN; j++)
        bfr[j] = *(const bf16x8*)&Bt[(wn * TN + j * 16 + m16) * 64 + s * 32 + quad * 8];
#pragma unroll
      for (int i = 0; i < FM; i++)
#pragma unroll
        for (int j = 0; j < FN; j++)
          acc[i][j] = __builtin_amdgcn_mfma_f32_16x16x32_bf16(af[i], bfr[j], acc[i][j], 0, 0, 0);
    }
    __syncthreads();
  }

  // C/D layout: col = lane&15, row = (lane>>4)*4 + reg  [verified m89/m91]
#pragma unroll
  for (int j = 0; j < FN; j++) {
    int col = col0 + wn * TN + j * 16 + m16;
    float bv = bias ? (float)bias[col] : 0.f;
#pragma unroll
    for (int i = 0; i < FM; i++) {
      int row = row0 + wm * TM + i * 16 + quad * 4;
#pragma unroll
      for (int r = 0; r < 4; r++) {
        float v = acc[i][j][r] * scale + bv;
        if (RELU) v = fmaxf(v, 0.f);
        Cb[(long)(row + r) * ldc + col] = (bf16)v;
      }
    }
  }
}

// ---------------------------------------------------------------------------
// Row softmax over S[bh][q][0:512], optional mask (-10000 where mask==0).
// ---------------------------------------------------------------------------
__global__ __launch_bounds__(256) void ksoftmax(
    bf16* __restrict__ S, const int* __restrict__ mask)
{
  int q = blockIdx.x, bh = blockIdx.y, b = bh >> 4;
  bf16* row = S + ((long)bh * SEQLEN + q) * SEQLEN;
  int t = threadIdx.x;
  float v0 = (float)row[t], v1 = (float)row[t + 256];
  if (mask) {
    const int* mrow = mask + ((long)b * SEQLEN + q) * SEQLEN;
    if (mrow[t] == 0)       v0 = -10000.f;
    if (mrow[t + 256] == 0) v1 = -10000.f;
  }
  float mx = fmaxf(v0, v1);
#pragma unroll
  for (int off = 32; off > 0; off >>= 1) mx = fmaxf(mx, __shfl_down(mx, off));
  __shared__ float r1[4], r2[4];
  if ((t & 63) == 0) r1[t >> 6] = mx;
  __syncthreads();
  mx = fmaxf(fmaxf(r1[0], r1[1]), fmaxf(r1[2], r1[3]));
  float e0 = __expf(v0 - mx), e1 = __expf(v1 - mx);
  float s = e0 + e1;
#pragma unroll
  for (int off = 32; off > 0; off >>= 1) s += __shfl_down(s, off);
  if ((t & 63) == 0) r2[t >> 6] = s;
  __syncthreads();
  float inv = 1.f / (r2[0] + r2[1] + r2[2] + r2[3]);
  row[t]       = (bf16)(e0 * inv);
  row[t + 256] = (bf16)(e1 * inv);
}

// ---------------------------------------------------------------------------
// Fused residual add + LayerNorm: x = LN(h + x) * g + b (fp32 math).
// ---------------------------------------------------------------------------
__global__ __launch_bounds__(256) void kaddln(
    const bf16* __restrict__ h, bf16* __restrict__ x,
    const bf16* __restrict__ g, const bf16* __restrict__ b)
{
  long row = blockIdx.x;
  const bf16* hr = h + row * DMODEL;
  bf16* xr = x + row * DMODEL;
  int t = threadIdx.x;
  bf16x4 hv = *(const bf16x4*)&hr[t * 4];
  bf16x4 xv = *(const bf16x4*)&xr[t * 4];
  float v[4]; float s1 = 0.f, s2 = 0.f;
#pragma unroll
  for (int i = 0; i < 4; i++) {
    v[i] = (float)hv[i] + (float)xv[i];
    s1 += v[i]; s2 += v[i] * v[i];
  }
#pragma unroll
  for (int off = 32; off > 0; off >>= 1) {
    s1 += __shfl_down(s1, off);
    s2 += __shfl_down(s2, off);
  }
  __shared__ float a1[4], a2[4];
  if ((t & 63) == 0) { a1[t >> 6] = s1; a2[t >> 6] = s2; }
  __syncthreads();
  s1 = a1[0] + a1[1] + a1[2] + a1[3];
  s2 = a2[0] + a2[1] + a2[2] + a2[3];
  float mean = s1 * (1.f / DMODEL);
  float var  = s2 * (1.f / DMODEL) - mean * mean;
  float rstd = rsqrtf(var + 1e-12f);
  bf16x4 gv = *(const bf16x4*)&g[t * 4];
  bf16x4 bv = *(const bf16x4*)&b[t * 4];
  bf16x4 o;
#pragma unroll
  for (int i = 0; i < 4; i++)
    o[i] = (bf16)(((v[i] - mean) * rstd) * (float)gv[i] + (float)bv[i]);
  *(bf16x4*)&xr[t * 4] = o;
}

// ---------------------------------------------------------------------------
extern "C" void kernel_launch(void* const* d_in, const int* in_sizes, int n_in,
                              void* d_out, int out_size, void* d_ws, size_t ws_size,
                              hipStream_t stream)
{
  (void)in_sizes; (void)n_in; (void)out_size; (void)ws_size;
  const void* trg_r  = d_in[0];
  const void* enc_r  = d_in[1];
  const int*  mask   = (const int*)d_in[2];
  const void* sa_w_r = d_in[3];
  const void* sa_b_r = d_in[4];
  const void* ca_w_r = d_in[5];
  const void* ca_b_r = d_in[6];
  const void* ln_g_r = d_in[7];
  const void* ln_b_r = d_in[8];
  const void* w1_r   = d_in[9];
  const void* b1_r   = d_in[10];
  const void* w2_r   = d_in[11];
  const void* b2_r   = d_in[12];

  const size_t XD = (size_t)MTOK * DMODEL;        // 4,194,304 elements
  char* p = (char*)d_ws;
  int*  flag = (int*)p;       p += 256;
  bf16* pSaB = (bf16*)p;      p += (size_t)NLAYER * 4 * DMODEL * 2;       // 48KB
  bf16* pCaB = (bf16*)p;      p += (size_t)NLAYER * 4 * DMODEL * 2;       // 48KB
  bf16* pLnG = (bf16*)p;      p += (size_t)NLAYER * 3 * DMODEL * 2;       // 36KB
  bf16* pLnB = (bf16*)p;      p += (size_t)NLAYER * 3 * DMODEL * 2;       // 36KB
  bf16* pB1  = (bf16*)p;      p += (size_t)NLAYER * FFDIM * 2;            // 48KB
  bf16* pB2  = (bf16*)p;      p += (size_t)NLAYER * DMODEL * 2;           // 12KB
  p = (char*)d_ws + (1 << 20);                                            // 1MB mark
  bf16* x    = (bf16*)p; p += XD * 2;
  bf16* encB = (bf16*)p; p += XD * 2;
  bf16* qb   = (bf16*)p; p += XD * 2;
  bf16* kb   = (bf16*)p; p += XD * 2;
  bf16* vb   = (bf16*)p; p += XD * 2;
  bf16* ob   = (bf16*)p; p += XD * 2;
  bf16* hb   = (bf16*)p; p += XD * 2;
  bf16* Vt   = (bf16*)p; p += (size_t)BATCH * NHEAD * DHEAD * SEQLEN * 2;  // 8MB
  bf16* Wt   = (bf16*)p; p += (size_t)4 * DMODEL * DMODEL * 2;             // 8MB
  bf16* big  = (bf16*)p; p += (size_t)BATCH * NHEAD * SEQLEN * SEQLEN * 2; // 64MB (Sb / ffh)
  bf16* Sb   = big;
  bf16* ffh  = big;

  const long PD = (long)SEQLEN * DMODEL;   // 524288
  const long SS = (long)SEQLEN * SEQLEN;   // 262144
  const long VS = (long)DHEAD * SEQLEN;    // 32768
  const long DD = (long)DMODEL * DMODEL;   // 1048576

  // --- dtype detection + input conversion (whole-model params once) ---
  kdetect<<<1, 256, 0, stream>>>((const unsigned short*)trg_r, flag);
  int nb = (int)((XD + 255) / 256);
  kcvt<<<nb, 256, 0, stream>>>(trg_r, x,    (long)XD, flag);
  kcvt<<<nb, 256, 0, stream>>>(enc_r, encB, (long)XD, flag);
  kcvt<<<96,  256, 0, stream>>>(sa_b_r, pSaB, (long)NLAYER * 4 * DMODEL, flag);
  kcvt<<<96,  256, 0, stream>>>(ca_b_r, pCaB, (long)NLAYER * 4 * DMODEL, flag);
  kcvt<<<72,  256, 0, stream>>>(ln_g_r, pLnG, (long)NLAYER * 3 * DMODEL, flag);
  kcvt<<<72,  256, 0, stream>>>(ln_b_r, pLnB, (long)NLAYER * 3 * DMODEL, flag);
  kcvt<<<96,  256, 0, stream>>>(b1_r,   pB1,  (long)NLAYER * FFDIM,      flag);
  kcvt<<<24,  256, 0, stream>>>(b2_r,   pB2,  (long)NLAYER * DMODEL,     flag);

  dim3 tb(32, 8, 1);
  for (int l = 0; l < NLAYER; l++) {
    for (int att = 0; att < 2; att++) {
      const void* Wraw = (att == 0) ? sa_w_r : ca_w_r;
      const bf16* Bv   = ((att == 0) ? pSaB : pCaB) + (size_t)l * 4 * DMODEL;
      const bf16* xkv  = (att == 0) ? x : encB;
      const int*  mk   = (att == 0) ? mask : nullptr;

      // transpose (+convert) 4 weights [K=1024][N=1024] -> Wt[i][N][K]
      ktranspose<<<dim3(32, 32, 4), tb, 0, stream>>>(
          Wraw, Wt, DMODEL, DMODEL, DMODEL, (long)l * 4 * DD, 0, DD, 4, DD, flag, 1);
      // q/k/v projections
      kgemm_nt<128,128,2,2,false><<<dim3(32, 8, 1), 256, 0, stream>>>(
          x,   Wt,          qb, Bv,            1024, 1024, 1024, 1024, 0,0,0,0,0,0, 1, 1.f);
      kgemm_nt<128,128,2,2,false><<<dim3(32, 8, 1), 256, 0, stream>>>(
          xkv, Wt + DD,     kb, Bv + DMODEL,   1024, 1024, 1024, 1024, 0,0,0,0,0,0, 1, 1.f);
      kgemm_nt<128,128,2,2,false><<<dim3(32, 8, 1), 256, 0, stream>>>(
          xkv, Wt + 2 * DD, vb, Bv + 2*DMODEL, 1024, 1024, 1024, 1024, 0,0,0,0,0,0, 1, 1.f);
      // S[bh] = (Q_bh @ K_bh^T) / 8  over 128 (b,h) pairs
      kgemm_nt<128,128,2,2,false><<<dim3(4, 4, 128), 256, 0, stream>>>(
          qb, kb, Sb, nullptr, 64, 1024, 1024, 512,
          PD, 64, PD, 64, 16 * SS, SS, 16, 0.125f);
      ksoftmax<<<dim3(512, 128), 256, 0, stream>>>(Sb, mk);
      // Vt[bh][d][j] = V[bh][j][d]
      ktranspose<<<dim3(16, 2, 128), tb, 0, stream>>>(
          vb, Vt, SEQLEN, DHEAD, DMODEL, 0, PD, 64, 16, VS, flag, 0);
      // O[bh] = P_bh @ V_bh
      kgemm_nt<128,64,2,2,false><<<dim3(4, 1, 128), 256, 0, stream>>>(
          Sb, Vt, ob, nullptr, 512, 512, 512, 1024,
          16 * SS, SS, 16 * VS, VS, PD, 64, 16, 1.f);
      // output projection -> hb
      kgemm_nt<128,128,2,2,false><<<dim3(32, 8, 1), 256, 0, stream>>>(
          ob, Wt + 3 * DD, hb, Bv + 3 * DMODEL, 1024, 1024, 1024, 1024, 0,0,0,0,0,0, 1, 1.f);
      // x = LN(hb + x)
      kaddln<<<dim3(MTOK), 256, 0, stream>>>(hb, x,
          pLnG + (size_t)(l * 3 + att) * DMODEL, pLnB + (size_t)(l * 3 + att) * DMODEL);
    }

    // ===================== FFN =====================
    ktranspose<<<dim3(32, 128, 1), tb, 0, stream>>>(
        w1_r, Wt, DMODEL, FFDIM, FFDIM, (long)l * DMODEL * FFDIM, 0, 0, 1, 0, flag, 1);
    kgemm_nt<128,128,2,2,true><<<dim3(32, 32, 1), 256, 0, stream>>>(
        x, Wt, ffh, pB1 + (size_t)l * FFDIM, 1024, 1024, 1024, 4096, 0,0,0,0,0,0, 1, 1.f);
    ktranspose<<<dim3(128, 32, 1), tb, 0, stream>>>(
        w2_r, Wt, FFDIM, DMODEL, DMODEL, (long)l * FFDIM * DMODEL, 0, 0, 1, 0, flag, 1);
    kgemm_nt<128,128,2,2,false><<<dim3(32, 8, 1), 256, 0, stream>>>(
        ffh, Wt, hb, pB2 + (size_t)l * DMODEL, 4096, 4096, 4096, 1024, 0,0,0,0,0,0, 1, 1.f);
    kaddln<<<dim3(MTOK), 256, 0, stream>>>(hb, x,
        pLnG + (size_t)(l * 3 + 2) * DMODEL, pLnB + (size_t)(l * 3 + 2) * DMODEL);
  }

  kout<<<nb, 256, 0, stream>>>(x, d_out, (long)XD, flag);
}

// Round 3
// 3504.465 us; speedup vs baseline: 1.1047x; 1.1047x over previous
//
#include <hip/hip_runtime.h>

typedef __bf16 bf16;
typedef __bf16 bf16x8 __attribute__((ext_vector_type(8)));
typedef __bf16 bf16x4 __attribute__((ext_vector_type(4)));
typedef float  f32x4  __attribute__((ext_vector_type(4)));

#define NLAYER 6
#define DMODEL 1024
#define NHEAD  16
#define DHEAD  64
#define FFDIM  4096
#define BATCH  8
#define SEQLEN 512
#define MTOK   (BATCH * SEQLEN)   // 4096 tokens
#define QKVLD  3072               // fused q|k|v row stride

#define GAS(p) ((const __attribute__((address_space(1))) void*)(p))
#define LAS(p) ((__attribute__((address_space(3))) void*)(p))

// ---------------------------------------------------------------------------
// Dtype detection: scan first 64K 16-bit words of trg. fp32 data -> ~128 words
// whose bf16-exponent bits are all-ones; bf16 N(0,1) data -> 0.
// flag=1 -> inputs are fp32;  flag=0 -> bf16.
// ---------------------------------------------------------------------------
__global__ __launch_bounds__(256) void kdetect(const unsigned short* __restrict__ w,
                                               int* __restrict__ flag)
{
  __shared__ int cnt;
  if (threadIdx.x == 0) cnt = 0;
  __syncthreads();
  int c = 0;
  for (int i = threadIdx.x; i < 65536; i += 256)
    c += (((w[i] >> 7) & 0xFF) == 0xFF);
  atomicAdd(&cnt, c);
  __syncthreads();
  if (threadIdx.x == 0) *flag = (cnt > 16) ? 1 : 0;
}

__global__ __launch_bounds__(256) void kcvt(const void* __restrict__ src,
                                            bf16* __restrict__ dst, long n,
                                            const int* __restrict__ flag)
{
  long i = (long)blockIdx.x * 256 + threadIdx.x;
  if (i >= n) return;
  if (*flag) dst[i] = (bf16)((const float*)src)[i];
  else       dst[i] = ((const bf16*)src)[i];
}

__global__ __launch_bounds__(256) void kout(const bf16* __restrict__ src,
                                            void* __restrict__ dst, long n,
                                            const int* __restrict__ flag)
{
  long i = (long)blockIdx.x * 256 + threadIdx.x;
  if (i >= n) return;
  if (*flag) ((float*)dst)[i] = (float)src[i];
  else       ((bf16*)dst)[i]  = src[i];
}

// ---------------------------------------------------------------------------
// Batched transpose with fused dtype conversion:
// in[ebase + z0*ibs0 + z1*ibs1 + r*ldin + c] -> out[z*obs + c*R + r]
// mode=1: source dtype per flag; mode=0: source is bf16. block (32,8).
// ---------------------------------------------------------------------------
__global__ __launch_bounds__(256) void ktranspose(
    const void* __restrict__ in, bf16* __restrict__ out,
    int R, int C, int ldin, long ebase, long ibs0, long ibs1, int nb1, long obs,
    const int* __restrict__ flag, int mode)
{
  __shared__ bf16 tile[32][33];
  bool f32in = mode && *flag;
  int z = blockIdx.z;
  long base = ebase + (long)(z / nb1) * ibs0 + (long)(z % nb1) * ibs1;
  bf16* dst = out + (long)z * obs;
  int r0 = blockIdx.x * 32, c0 = blockIdx.y * 32;
  int tx = threadIdx.x, ty = threadIdx.y;
  const float* fp = (const float*)in;
  const bf16*  bp = (const bf16*)in;
#pragma unroll
  for (int i = 0; i < 32; i += 8) {
    long idx = base + (long)(r0 + ty + i) * ldin + (c0 + tx);
    tile[ty + i][tx] = f32in ? (bf16)fp[idx] : bp[idx];
  }
  __syncthreads();
#pragma unroll
  for (int i = 0; i < 32; i += 8)
    dst[(long)(c0 + ty + i) * R + (r0 + tx)] = tile[tx][ty + i];
}

// ---------------------------------------------------------------------------
// Batched NT GEMM: C[M,N] = scale * (A[M,K] @ B[N,K]^T) + bias[N], opt ReLU.
// A, B row-major bf16, K contiguous; fp32 MFMA accumulate (m97 structure).
// Tile BMxBN, 4 waves (WMxWN). 64x128 variant for skinny-N (2 blocks/CU).
// ---------------------------------------------------------------------------
template<int BM, int BN, int WM, int WN, bool RELU>
__global__ __launch_bounds__(256) void kgemm_nt(
    const bf16* __restrict__ A, const bf16* __restrict__ B, bf16* __restrict__ C,
    const bf16* __restrict__ bias, int K, int lda, int ldb, int ldc,
    long aB0, long aB1, long bB0, long bB1, long cB0, long cB1,
    int nb1, float scale)
{
  constexpr int TM = BM / WM, TN = BN / WN;
  constexpr int FM = TM / 16, FN = TN / 16;
  __shared__ __align__(16) bf16 At[BM * 64];
  __shared__ __align__(16) bf16 Bt[BN * 64];

  int z = blockIdx.z, z0 = z / nb1, z1 = z % nb1;
  const bf16* Ab = A + z0 * aB0 + z1 * aB1;
  const bf16* Bb = B + z0 * bB0 + z1 * bB1;
  bf16* Cb = C + z0 * cB0 + z1 * cB1;

  int row0 = blockIdx.x * BM, col0 = blockIdx.y * BN;
  int t = threadIdx.x;
  int lane = t & 63, w = t >> 6;
  int wm = w / WN, wn = w % WN;
  int m16 = lane & 15, quad = lane >> 4;

  f32x4 acc[FM][FN];
#pragma unroll
  for (int i = 0; i < FM; i++)
#pragma unroll
    for (int j = 0; j < FN; j++)
      acc[i][j] = f32x4{0.f, 0.f, 0.f, 0.f};

  int sr = t >> 3, sc = (t & 7) * 8;     // thread t stages 16B: row t/8, col (t%8)*8
  const bf16* ga = Ab + (long)(row0 + sr) * lda + sc;
  const bf16* gb = Bb + (long)(col0 + sr) * ldb + sc;

  for (int k0 = 0; k0 < K; k0 += 64) {
#pragma unroll
    for (int i = 0; i < BM / 32; i++)
      __builtin_amdgcn_global_load_lds(GAS(ga + (long)i * 32 * lda + k0),
                                       LAS(&At[t * 8 + i * 2048]), 16, 0, 0);
#pragma unroll
    for (int i = 0; i < BN / 32; i++)
      __builtin_amdgcn_global_load_lds(GAS(gb + (long)i * 32 * ldb + k0),
                                       LAS(&Bt[t * 8 + i * 2048]), 16, 0, 0);
    __syncthreads();
#pragma unroll
    for (int s = 0; s < 2; s++) {
      bf16x8 af[FM], bfr[FN];
#pragma unroll
      for (int i = 0; i < FM; i++)
        af[i] = *(const bf16x8*)&At[(wm * TM + i * 16 + m16) * 64 + s * 32 + quad * 8];
#pragma unroll
      for (int j = 0; j < FN; j++)
        bfr[j] = *(const bf16x8*)&Bt[(wn * TN + j * 16 + m16) * 64 + s * 32 + quad * 8];
#pragma unroll
      for (int i = 0; i < FM; i++)
#pragma unroll
        for (int j = 0; j < FN; j++)
          acc[i][j] = __builtin_amdgcn_mfma_f32_16x16x32_bf16(af[i], bfr[j], acc[i][j], 0, 0, 0);
    }
    __syncthreads();
  }

  // C/D layout: col = lane&15, row = (lane>>4)*4 + reg  [verified m89/m91]
#pragma unroll
  for (int j = 0; j < FN; j++) {
    int col = col0 + wn * TN + j * 16 + m16;
    float bv = bias ? (float)bias[col] : 0.f;
#pragma unroll
    for (int i = 0; i < FM; i++) {
      int row = row0 + wm * TM + i * 16 + quad * 4;
#pragma unroll
      for (int r = 0; r < 4; r++) {
        float v = acc[i][j][r] * scale + bv;
        if (RELU) v = fmaxf(v, 0.f);
        Cb[(long)(row + r) * ldc + col] = (bf16)v;
      }
    }
  }
}

// ---------------------------------------------------------------------------
// Row softmax over S[bh][q][0:512], optional mask (-10000 where mask==0).
// ---------------------------------------------------------------------------
__global__ __launch_bounds__(256) void ksoftmax(
    bf16* __restrict__ S, const int* __restrict__ mask)
{
  int q = blockIdx.x, bh = blockIdx.y, b = bh >> 4;
  bf16* row = S + ((long)bh * SEQLEN + q) * SEQLEN;
  int t = threadIdx.x;
  float v0 = (float)row[t], v1 = (float)row[t + 256];
  if (mask) {
    const int* mrow = mask + ((long)b * SEQLEN + q) * SEQLEN;
    if (mrow[t] == 0)       v0 = -10000.f;
    if (mrow[t + 256] == 0) v1 = -10000.f;
  }
  float mx = fmaxf(v0, v1);
#pragma unroll
  for (int off = 32; off > 0; off >>= 1) mx = fmaxf(mx, __shfl_down(mx, off));
  __shared__ float r1[4], r2[4];
  if ((t & 63) == 0) r1[t >> 6] = mx;
  __syncthreads();
  mx = fmaxf(fmaxf(r1[0], r1[1]), fmaxf(r1[2], r1[3]));
  float e0 = __expf(v0 - mx), e1 = __expf(v1 - mx);
  float s = e0 + e1;
#pragma unroll
  for (int off = 32; off > 0; off >>= 1) s += __shfl_down(s, off);
  if ((t & 63) == 0) r2[t >> 6] = s;
  __syncthreads();
  float inv = 1.f / (r2[0] + r2[1] + r2[2] + r2[3]);
  row[t]       = (bf16)(e0 * inv);
  row[t + 256] = (bf16)(e1 * inv);
}

// ---------------------------------------------------------------------------
// Fused residual add + LayerNorm: x = LN(h + x) * g + b (fp32 math).
// ---------------------------------------------------------------------------
__global__ __launch_bounds__(256) void kaddln(
    const bf16* __restrict__ h, bf16* __restrict__ x,
    const bf16* __restrict__ g, const bf16* __restrict__ b)
{
  long row = blockIdx.x;
  const bf16* hr = h + row * DMODEL;
  bf16* xr = x + row * DMODEL;
  int t = threadIdx.x;
  bf16x4 hv = *(const bf16x4*)&hr[t * 4];
  bf16x4 xv = *(const bf16x4*)&xr[t * 4];
  float v[4]; float s1 = 0.f, s2 = 0.f;
#pragma unroll
  for (int i = 0; i < 4; i++) {
    v[i] = (float)hv[i] + (float)xv[i];
    s1 += v[i]; s2 += v[i] * v[i];
  }
#pragma unroll
  for (int off = 32; off > 0; off >>= 1) {
    s1 += __shfl_down(s1, off);
    s2 += __shfl_down(s2, off);
  }
  __shared__ float a1[4], a2[4];
  if ((t & 63) == 0) { a1[t >> 6] = s1; a2[t >> 6] = s2; }
  __syncthreads();
  s1 = a1[0] + a1[1] + a1[2] + a1[3];
  s2 = a2[0] + a2[1] + a2[2] + a2[3];
  float mean = s1 * (1.f / DMODEL);
  float var  = s2 * (1.f / DMODEL) - mean * mean;
  float rstd = rsqrtf(var + 1e-12f);
  bf16x4 gv = *(const bf16x4*)&g[t * 4];
  bf16x4 bv = *(const bf16x4*)&b[t * 4];
  bf16x4 o;
#pragma unroll
  for (int i = 0; i < 4; i++)
    o[i] = (bf16)(((v[i] - mean) * rstd) * (float)gv[i] + (float)bv[i]);
  *(bf16x4*)&xr[t * 4] = o;
}

// ---------------------------------------------------------------------------
extern "C" void kernel_launch(void* const* d_in, const int* in_sizes, int n_in,
                              void* d_out, int out_size, void* d_ws, size_t ws_size,
                              hipStream_t stream)
{
  (void)in_sizes; (void)n_in; (void)out_size; (void)ws_size;
  const void* trg_r  = d_in[0];
  const void* enc_r  = d_in[1];
  const int*  mask   = (const int*)d_in[2];
  const void* sa_w_r = d_in[3];
  const void* sa_b_r = d_in[4];
  const void* ca_w_r = d_in[5];
  const void* ca_b_r = d_in[6];
  const void* ln_g_r = d_in[7];
  const void* ln_b_r = d_in[8];
  const void* w1_r   = d_in[9];
  const void* b1_r   = d_in[10];
  const void* w2_r   = d_in[11];
  const void* b2_r   = d_in[12];

  const size_t XD = (size_t)MTOK * DMODEL;        // 4,194,304 elements
  char* p = (char*)d_ws;
  int*  flag = (int*)p;       p += 256;
  bf16* pSaB = (bf16*)p;      p += (size_t)NLAYER * 4 * DMODEL * 2;
  bf16* pCaB = (bf16*)p;      p += (size_t)NLAYER * 4 * DMODEL * 2;
  bf16* pLnG = (bf16*)p;      p += (size_t)NLAYER * 3 * DMODEL * 2;
  bf16* pLnB = (bf16*)p;      p += (size_t)NLAYER * 3 * DMODEL * 2;
  bf16* pB1  = (bf16*)p;      p += (size_t)NLAYER * FFDIM * 2;
  bf16* pB2  = (bf16*)p;      p += (size_t)NLAYER * DMODEL * 2;
  p = (char*)d_ws + (1 << 20);                                             // 1MB mark
  bf16* x    = (bf16*)p; p += XD * 2;                                      // 8MB
  bf16* encB = (bf16*)p; p += XD * 2;                                      // 8MB
  bf16* qkv  = (bf16*)p; p += (size_t)MTOK * QKVLD * 2;                    // 24MB
  bf16* ob   = (bf16*)p; p += XD * 2;                                      // 8MB
  bf16* hb   = (bf16*)p; p += XD * 2;                                      // 8MB
  bf16* Vt   = (bf16*)p; p += (size_t)BATCH * NHEAD * DHEAD * SEQLEN * 2;  // 8MB
  bf16* Wt   = (bf16*)p; p += (size_t)4 * DMODEL * DMODEL * 2;             // 8MB
  bf16* big  = (bf16*)p; p += (size_t)BATCH * NHEAD * SEQLEN * SEQLEN * 2; // 64MB
  bf16* Sb   = big;
  bf16* ffh  = big;

  const long PQ = (long)SEQLEN * QKVLD;    // 1572864: batch stride in qkv buffer
  const long PD = (long)SEQLEN * DMODEL;   // 524288
  const long SS = (long)SEQLEN * SEQLEN;   // 262144
  const long VS = (long)DHEAD * SEQLEN;    // 32768
  const long DD = (long)DMODEL * DMODEL;   // 1048576

  // --- dtype detection + input conversion ---
  kdetect<<<1, 256, 0, stream>>>((const unsigned short*)trg_r, flag);
  int nb = (int)((XD + 255) / 256);
  kcvt<<<nb, 256, 0, stream>>>(trg_r, x,    (long)XD, flag);
  kcvt<<<nb, 256, 0, stream>>>(enc_r, encB, (long)XD, flag);
  kcvt<<<96,  256, 0, stream>>>(sa_b_r, pSaB, (long)NLAYER * 4 * DMODEL, flag);
  kcvt<<<96,  256, 0, stream>>>(ca_b_r, pCaB, (long)NLAYER * 4 * DMODEL, flag);
  kcvt<<<72,  256, 0, stream>>>(ln_g_r, pLnG, (long)NLAYER * 3 * DMODEL, flag);
  kcvt<<<72,  256, 0, stream>>>(ln_b_r, pLnB, (long)NLAYER * 3 * DMODEL, flag);
  kcvt<<<96,  256, 0, stream>>>(b1_r,   pB1,  (long)NLAYER * FFDIM,      flag);
  kcvt<<<24,  256, 0, stream>>>(b2_r,   pB2,  (long)NLAYER * DMODEL,     flag);

  dim3 tb(32, 8, 1);
  for (int l = 0; l < NLAYER; l++) {
    for (int att = 0; att < 2; att++) {
      const void* Wraw = (att == 0) ? sa_w_r : ca_w_r;
      const bf16* Bv   = ((att == 0) ? pSaB : pCaB) + (size_t)l * 4 * DMODEL;
      const int*  mk   = (att == 0) ? mask : nullptr;

      // transpose (+convert) 4 weights [K][N] -> Wt[i][N][K]; q|k|v contiguous
      ktranspose<<<dim3(32, 32, 4), tb, 0, stream>>>(
          Wraw, Wt, DMODEL, DMODEL, DMODEL, (long)l * 4 * DD, 0, DD, 4, DD, flag, 1);
      if (att == 0) {
        // fused QKV: [4096,1024] @ [3072,1024]^T -> qkv[4096,3072] (768 blocks)
        kgemm_nt<128,128,2,2,false><<<dim3(32, 24, 1), 256, 0, stream>>>(
            x, Wt, qkv, Bv, 1024, 1024, 1024, QKVLD, 0,0,0,0,0,0, 1, 1.f);
      } else {
        // Q from x (512 blocks, 64x128 tile); K|V fused from enc (512 blocks)
        kgemm_nt<64,128,2,2,false><<<dim3(64, 8, 1), 256, 0, stream>>>(
            x, Wt, qkv, Bv, 1024, 1024, 1024, QKVLD, 0,0,0,0,0,0, 1, 1.f);
        kgemm_nt<128,128,2,2,false><<<dim3(32, 16, 1), 256, 0, stream>>>(
            encB, Wt + DD, qkv + 1024, Bv + 1024, 1024, 1024, 1024, QKVLD,
            0,0,0,0,0,0, 1, 1.f);
      }
      // S[bh] = (Q_bh @ K_bh^T) / 8  over 128 (b,h) pairs (2048 blocks)
      kgemm_nt<128,128,2,2,false><<<dim3(4, 4, 128), 256, 0, stream>>>(
          qkv, qkv + 1024, Sb, nullptr, 64, QKVLD, QKVLD, 512,
          PQ, 64, PQ, 64, 16 * SS, SS, 16, 0.125f);
      ksoftmax<<<dim3(512, 128), 256, 0, stream>>>(Sb, mk);
      // Vt[bh][d][j] = V[bh][j][d]
      ktranspose<<<dim3(16, 2, 128), tb, 0, stream>>>(
          qkv + 2048, Vt, SEQLEN, DHEAD, QKVLD, 0, PQ, 64, 16, VS, flag, 0);
      // O[bh] = P_bh @ V_bh (512 blocks)
      kgemm_nt<128,64,2,2,false><<<dim3(4, 1, 128), 256, 0, stream>>>(
          Sb, Vt, ob, nullptr, 512, 512, 512, 1024,
          16 * SS, SS, 16 * VS, VS, PD, 64, 16, 1.f);
      // output projection (512 blocks, 64x128 tile)
      kgemm_nt<64,128,2,2,false><<<dim3(64, 8, 1), 256, 0, stream>>>(
          ob, Wt + 3 * DD, hb, Bv + 3 * DMODEL, 1024, 1024, 1024, 1024,
          0,0,0,0,0,0, 1, 1.f);
      // x = LN(hb + x)
      kaddln<<<dim3(MTOK), 256, 0, stream>>>(hb, x,
          pLnG + (size_t)(l * 3 + att) * DMODEL, pLnB + (size_t)(l * 3 + att) * DMODEL);
    }

    // ===================== FFN =====================
    ktranspose<<<dim3(32, 128, 1), tb, 0, stream>>>(
        w1_r, Wt, DMODEL, FFDIM, FFDIM, (long)l * DMODEL * FFDIM, 0, 0, 1, 0, flag, 1);
    kgemm_nt<128,128,2,2,true><<<dim3(32, 32, 1), 256, 0, stream>>>(
        x, Wt, ffh, pB1 + (size_t)l * FFDIM, 1024, 1024, 1024, 4096,
        0,0,0,0,0,0, 1, 1.f);
    ktranspose<<<dim3(128, 32, 1), tb, 0, stream>>>(
        w2_r, Wt, FFDIM, DMODEL, DMODEL, (long)l * FFDIM * DMODEL, 0, 0, 1, 0, flag, 1);
    // FFN down: 64x128 tile -> 512 blocks, 2/CU
    kgemm_nt<64,128,2,2,false><<<dim3(64, 8, 1), 256, 0, stream>>>(
        ffh, Wt, hb, pB2 + (size_t)l * DMODEL, 4096, 4096, 4096, 1024,
        0,0,0,0,0,0, 1, 1.f);
    kaddln<<<dim3(MTOK), 256, 0, stream>>>(hb, x,
        pLnG + (size_t)(l * 3 + 2) * DMODEL, pLnB + (size_t)(l * 3 + 2) * DMODEL);
  }

  kout<<<nb, 256, 0, stream>>>(x, d_out, (long)XD, flag);
}